// Round 6
// baseline (611.473 us; speedup 1.0000x reference)
//
#include <hip/hip_runtime.h>
#include <hip/hip_bf16.h>
#include <math.h>

// GAT 2-layer, MI355X. CSR aggregation, XCD-feature-sliced gathers (r6),
// MFMA GEMMs (3-term bf16 split ~ f32 accuracy).
#define NN 50000
#define NE 800000
#define ET 850000          // NE + NN self loops
#define DIN 512
#define F1 128             // HEADS*HIDDEN
#define NC 40
#define NEG 0.2f
#define CAP 128            // per-node cached-edge cap (max degree ~50 stat.)
#define SCAN_NB ((NN + 255) / 256)   // 196

typedef __attribute__((ext_vector_type(8))) short s16x8;
typedef __attribute__((ext_vector_type(4))) float f32x4;

__device__ inline unsigned short bfh(float f) {
    __hip_bfloat16 h = __float2bfloat16(f);
    return __builtin_bit_cast(unsigned short, h);
}
__device__ inline float bff(unsigned short u) {
    unsigned int x = (unsigned int)u << 16;
    return __builtin_bit_cast(float, x);
}

__device__ inline void split8(f32x4 v0, f32x4 v1, s16x8* hi, s16x8* lo) {
    float f[8] = {v0.x, v0.y, v0.z, v0.w, v1.x, v1.y, v1.z, v1.w};
    #pragma unroll
    for (int j = 0; j < 8; ++j) {
        unsigned short h = bfh(f[j]);
        (*hi)[j] = (short)h;
        (*lo)[j] = (short)bfh(f[j] - bff(h));
    }
}

__device__ inline void gl16(const void* g, void* l) {
    __builtin_amdgcn_global_load_lds((const __attribute__((address_space(1))) unsigned int*)g,
                                     (__attribute__((address_space(3))) unsigned int*)l, 16, 0, 0);
}

// ---------------- prep: zero deg + weight splits (merged) ----------------
__global__ void prep_kernel(const float* __restrict__ W1,
        const float* __restrict__ W2, int* __restrict__ deg,
        unsigned short* __restrict__ Wh1T, unsigned short* __restrict__ Wl1T,
        unsigned short* __restrict__ Wh2T, unsigned short* __restrict__ Wl2T) {
    int i = blockIdx.x * blockDim.x + threadIdx.x;
    if (i < NN) deg[i] = 0;
    if (i < DIN * F1) {
        int k = i >> 7, c = i & 127;
        float w = W1[i];
        unsigned short h = bfh(w);
        unsigned short l = bfh(w - bff(h));
        Wh1T[c * DIN + k] = h;
        Wl1T[c * DIN + k] = l;
    }
    if (i < 48 * 128) {
        int c = i >> 7, k = i & 127;
        float w = (c < NC) ? W2[k * NC + c] : 0.f;
        unsigned short h = bfh(w);
        unsigned short l = bfh(w - bff(h));
        Wh2T[c * 128 + k] = h;
        Wl2T[c * 128 + k] = l;
    }
}

// ---------------- CSR build ----------------
__global__ void hist_kernel(const int* __restrict__ dst, int* __restrict__ deg) {
    int e = blockIdx.x * blockDim.x + threadIdx.x;
    if (e >= ET) return;
    int d = (e < NE) ? dst[e] : (e - NE);
    atomicAdd(&deg[d], 1);
}

__global__ __launch_bounds__(256) void partial_kernel(const int* __restrict__ deg,
        int* __restrict__ bsum) {
    __shared__ int red[4];
    int i = blockIdx.x * 256 + threadIdx.x;
    int v = (i < NN) ? deg[i] : 0;
    #pragma unroll
    for (int o = 1; o < 64; o <<= 1) v += __shfl_xor(v, o);
    if ((threadIdx.x & 63) == 0) red[threadIdx.x >> 6] = v;
    __syncthreads();
    if (threadIdx.x == 0) bsum[blockIdx.x] = red[0] + red[1] + red[2] + red[3];
}

__global__ __launch_bounds__(256) void scanp_kernel(const int* __restrict__ bsum,
        int* __restrict__ bbase) {
    __shared__ int s[256];
    int t = threadIdx.x;
    s[t] = (t < SCAN_NB) ? bsum[t] : 0;
    __syncthreads();
    #pragma unroll
    for (int o = 1; o < 256; o <<= 1) {
        int v = (t >= o) ? s[t - o] : 0;
        __syncthreads();
        s[t] += v;
        __syncthreads();
    }
    if (t < SCAN_NB) bbase[t] = (t == 0) ? 0 : s[t - 1];
}

__global__ __launch_bounds__(256) void emit_kernel(const int* __restrict__ deg,
        const int* __restrict__ bbase, int* __restrict__ off, int* __restrict__ cur) {
    __shared__ int s[256];
    int t = threadIdx.x;
    int i = blockIdx.x * 256 + t;
    int d = (i < NN) ? deg[i] : 0;
    s[t] = d;
    __syncthreads();
    #pragma unroll
    for (int o = 1; o < 256; o <<= 1) {
        int v = (t >= o) ? s[t - o] : 0;
        __syncthreads();
        s[t] += v;
        __syncthreads();
    }
    int o0 = bbase[blockIdx.x] + s[t] - d;   // exclusive
    if (i < NN) { off[i] = o0; cur[i] = o0; }
    if (i == NN - 1) off[NN] = o0 + d;
}

__global__ void scatter_kernel(const int* __restrict__ src, const int* __restrict__ dst,
        int* __restrict__ cur, int* __restrict__ ssorted) {
    int e = blockIdx.x * blockDim.x + threadIdx.x;
    if (e >= ET) return;
    int s = (e < NE) ? src[e] : (e - NE);
    int d = (e < NE) ? dst[e] : (e - NE);
    int pos = atomicAdd(&cur[d], 1);
    ssorted[pos] = s;
}

// ---------------- GEMM1 MFMA: [NN,512] x [512,128] -> hpre, + fused scores ----------------
__global__ __launch_bounds__(256) void gemm1_mfma(const float* __restrict__ X,
        const unsigned short* __restrict__ BhT, const unsigned short* __restrict__ BlT,
        const float* __restrict__ a_src, const float* __restrict__ a_dst,
        float* __restrict__ H, float* __restrict__ s1s, float* __restrict__ s1d) {
    __shared__ char lds[49152];               // Ah 8K | Al 8K | Bh 16K | Bl 16K
    char* ldsAh = lds;
    char* ldsAl = lds + 8192;
    char* ldsBh = lds + 16384;
    char* ldsBl = lds + 32768;
    const int tid = threadIdx.x;
    const int wid = tid >> 6, lane = tid & 63;
    const int wm = wid >> 1, wn = wid & 1;
    const int l15 = lane & 15, lg = lane >> 4;
    const int row0 = blockIdx.x * 64;

    const int arow = tid >> 2;
    const int akc  = (tid & 3) * 16;
    const int asw  = (arow & 7) << 4;
    int agr = row0 + arow; if (agr > NN - 1) agr = NN - 1;
    const float* aptr = X + (long)agr * DIN + akc;

    f32x4 acc[2][4];
    #pragma unroll
    for (int mi = 0; mi < 2; ++mi)
        #pragma unroll
        for (int ni = 0; ni < 4; ++ni) acc[mi][ni] = (f32x4)(0.f);

    for (int k0 = 0; k0 < DIN; k0 += 64) {
        #pragma unroll
        for (int p = 0; p < 4; ++p) {
            int q = p * 256 + tid;
            int dstoff = (p * 256 + wid * 64) << 4;
            int rr = q >> 3;
            int w = (q & 7) << 4;
            int sw = (rr & 7) << 4;
            long sb = (long)rr * (DIN * 2) + k0 * 2 + (w ^ sw);
            gl16((const char*)BhT + sb, ldsBh + dstoff);
            gl16((const char*)BlT + sb, ldsBl + dstoff);
        }
        {
            f32x4 v0 = *(const f32x4*)(aptr + k0);
            f32x4 v1 = *(const f32x4*)(aptr + k0 + 4);
            f32x4 v2 = *(const f32x4*)(aptr + k0 + 8);
            f32x4 v3 = *(const f32x4*)(aptr + k0 + 12);
            s16x8 h0, l0, h1, l1;
            split8(v0, v1, &h0, &l0);
            split8(v2, v3, &h1, &l1);
            int b0 = arow * 128 + ((akc * 2) ^ asw);
            int b1 = arow * 128 + ((akc * 2 + 16) ^ asw);
            *(s16x8*)(ldsAh + b0) = h0;
            *(s16x8*)(ldsAh + b1) = h1;
            *(s16x8*)(ldsAl + b0) = l0;
            *(s16x8*)(ldsAl + b1) = l1;
        }
        __syncthreads();
        #pragma unroll
        for (int ks = 0; ks < 2; ++ks) {
            s16x8 ah[2], al[2], bh[4], bl[4];
            #pragma unroll
            for (int mi = 0; mi < 2; ++mi) {
                int row = wm * 32 + mi * 16 + l15;
                int sw = (row & 7) << 4;
                int kb = (ks * 32 + lg * 8) * 2;
                ah[mi] = *(const s16x8*)(ldsAh + row * 128 + (kb ^ sw));
                al[mi] = *(const s16x8*)(ldsAl + row * 128 + (kb ^ sw));
            }
            #pragma unroll
            for (int ni = 0; ni < 4; ++ni) {
                int col = wn * 64 + ni * 16 + l15;
                int sw = (col & 7) << 4;
                int kb = (ks * 32 + lg * 8) * 2;
                bh[ni] = *(const s16x8*)(ldsBh + col * 128 + (kb ^ sw));
                bl[ni] = *(const s16x8*)(ldsBl + col * 128 + (kb ^ sw));
            }
            #pragma unroll
            for (int mi = 0; mi < 2; ++mi)
                #pragma unroll
                for (int ni = 0; ni < 4; ++ni) {
                    acc[mi][ni] = __builtin_amdgcn_mfma_f32_16x16x32_bf16(ah[mi], bh[ni], acc[mi][ni], 0, 0, 0);
                    acc[mi][ni] = __builtin_amdgcn_mfma_f32_16x16x32_bf16(ah[mi], bl[ni], acc[mi][ni], 0, 0, 0);
                    acc[mi][ni] = __builtin_amdgcn_mfma_f32_16x16x32_bf16(al[mi], bh[ni], acc[mi][ni], 0, 0, 0);
                }
        }
        __syncthreads();
    }

    #pragma unroll
    for (int mi = 0; mi < 2; ++mi)
        #pragma unroll
        for (int ni = 0; ni < 4; ++ni) {
            int col = wn * 64 + ni * 16 + l15;
            #pragma unroll
            for (int r = 0; r < 4; ++r) {
                int grow = row0 + wm * 32 + mi * 16 + lg * 4 + r;
                if (grow < NN) H[(long)grow * F1 + col] = acc[mi][ni][r];
            }
        }
    float av[4], bv[4];
    #pragma unroll
    for (int ni = 0; ni < 4; ++ni) {
        int col = wn * 64 + ni * 16 + l15;
        av[ni] = a_src[col];
        bv[ni] = a_dst[col];
    }
    #pragma unroll
    for (int mi = 0; mi < 2; ++mi)
        #pragma unroll
        for (int hl = 0; hl < 2; ++hl) {
            #pragma unroll
            for (int r = 0; r < 4; ++r) {
                float t1 = acc[mi][2 * hl][r] * av[2 * hl] + acc[mi][2 * hl + 1][r] * av[2 * hl + 1];
                float t2 = acc[mi][2 * hl][r] * bv[2 * hl] + acc[mi][2 * hl + 1][r] * bv[2 * hl + 1];
                #pragma unroll
                for (int o = 1; o < 16; o <<= 1) {
                    t1 += __shfl_xor(t1, o);
                    t2 += __shfl_xor(t2, o);
                }
                int grow = row0 + wm * 32 + mi * 16 + lg * 4 + r;
                if (l15 == 0 && grow < NN) {
                    int head = 2 * wn + hl;
                    s1s[grow * 4 + head] = t1;
                    s1d[grow * 4 + head] = t2;
                }
            }
        }
}

// ---------------- GEMM2 MFMA: [NN,128] x [128,40->48] -> Z, + fused scores ----------------
__global__ __launch_bounds__(256) void gemm2_mfma(const float* __restrict__ H1,
        const unsigned short* __restrict__ B2h, const unsigned short* __restrict__ B2l,
        const float* __restrict__ a_src, const float* __restrict__ a_dst,
        float* __restrict__ Z, float* __restrict__ s2s, float* __restrict__ s2d) {
    __shared__ char lds[57344];               // A 32K | Bh 12K | Bl 12K
    char* ldsA  = lds;
    char* ldsBh = lds + 32768;
    char* ldsBl = lds + 45056;
    const int tid = threadIdx.x;
    const int wid = tid >> 6, lane = tid & 63;
    const int l15 = lane & 15, lg = lane >> 4;
    const int row0 = blockIdx.x * 64;

    #pragma unroll
    for (int p = 0; p < 8; ++p) {
        int q = p * 256 + tid;
        int row = q >> 5;
        int w = (q & 31) << 4;
        int sw = (row & 7) << 4;
        int gr = row0 + row; if (gr > NN - 1) gr = NN - 1;
        gl16((const char*)(H1 + (long)gr * F1) + (w ^ sw), ldsA + ((p * 256 + wid * 64) << 4));
    }
    #pragma unroll
    for (int p = 0; p < 3; ++p) {
        int q = p * 256 + tid;
        int rr = q >> 4;
        int w = (q & 15) << 4;
        int sw = (rr & 7) << 4;
        int dstoff = (p * 256 + wid * 64) << 4;
        gl16((const char*)B2h + rr * 256 + (w ^ sw), ldsBh + dstoff);
        gl16((const char*)B2l + rr * 256 + (w ^ sw), ldsBl + dstoff);
    }
    __syncthreads();

    f32x4 acc[3];
    #pragma unroll
    for (int ni = 0; ni < 3; ++ni) acc[ni] = (f32x4)(0.f);

    #pragma unroll
    for (int ks = 0; ks < 4; ++ks) {
        int row = wid * 16 + l15;
        int sw = (row & 7) << 4;
        int kb = (ks * 32 + lg * 8) * 4;
        f32x4 v0 = *(const f32x4*)(ldsA + row * 512 + ((kb)      ^ sw));
        f32x4 v1 = *(const f32x4*)(ldsA + row * 512 + ((kb + 16) ^ sw));
        s16x8 ah, al;
        split8(v0, v1, &ah, &al);
        #pragma unroll
        for (int ni = 0; ni < 3; ++ni) {
            int cc = ni * 16 + l15;
            int swb = (cc & 7) << 4;
            int kb2 = (ks * 32 + lg * 8) * 2;
            s16x8 bh = *(const s16x8*)(ldsBh + cc * 256 + (kb2 ^ swb));
            s16x8 bl = *(const s16x8*)(ldsBl + cc * 256 + (kb2 ^ swb));
            acc[ni] = __builtin_amdgcn_mfma_f32_16x16x32_bf16(ah, bh, acc[ni], 0, 0, 0);
            acc[ni] = __builtin_amdgcn_mfma_f32_16x16x32_bf16(ah, bl, acc[ni], 0, 0, 0);
            acc[ni] = __builtin_amdgcn_mfma_f32_16x16x32_bf16(al, bh, acc[ni], 0, 0, 0);
        }
    }

    float av[3], bv[3];
    #pragma unroll
    for (int ni = 0; ni < 3; ++ni) {
        int cc = ni * 16 + l15;
        av[ni] = (cc < NC) ? a_src[cc] : 0.f;
        bv[ni] = (cc < NC) ? a_dst[cc] : 0.f;
    }
    #pragma unroll
    for (int r = 0; r < 4; ++r) {
        int grow = row0 + wid * 16 + lg * 4 + r;
        bool ok = grow < NN;
        float t1 = acc[0][r] * av[0] + acc[1][r] * av[1] + acc[2][r] * av[2];
        float t2 = acc[0][r] * bv[0] + acc[1][r] * bv[1] + acc[2][r] * bv[2];
        #pragma unroll
        for (int o = 1; o < 16; o <<= 1) {
            t1 += __shfl_xor(t1, o);
            t2 += __shfl_xor(t2, o);
        }
        #pragma unroll
        for (int ni = 0; ni < 3; ++ni) {
            int cc = ni * 16 + l15;
            if (ok && cc < NC) Z[(long)grow * NC + cc] = acc[ni][r];
        }
        if (ok && l15 == 0) { s2s[grow] = t1; s2d[grow] = t2; }
    }
}

// ------------- alpha1: per-node softmax -> normalized alphas [ET][4] -------------
__global__ __launch_bounds__(256) void alpha1_kernel(
        const int* __restrict__ off, const int* __restrict__ ssorted,
        const float* __restrict__ ssrc, const float* __restrict__ sdst,
        float* __restrict__ alphaN) {
    __shared__ __align__(16) float e_lds[4][CAP][4];
    const int nd = threadIdx.x >> 6;
    int n = blockIdx.x * 4 + nd;
    if (n >= NN) return;
    const int lane = threadIdx.x & 63;
    const int base = off[n];
    const int deg  = off[n + 1] - base;
    const float4 vd = *(const float4*)(sdst + (long)n * 4);

    // sweep 1: logits -> LDS, track max
    float m0 = -1e30f, m1 = -1e30f, m2 = -1e30f, m3 = -1e30f;
    for (int k = lane; k < deg; k += 64) {
        int s = ssorted[base + k];
        float4 vs = *(const float4*)(ssrc + (long)s * 4);
        float x0 = vs.x + vd.x; x0 = (x0 > 0.f) ? x0 : NEG * x0;
        float x1 = vs.y + vd.y; x1 = (x1 > 0.f) ? x1 : NEG * x1;
        float x2 = vs.z + vd.z; x2 = (x2 > 0.f) ? x2 : NEG * x2;
        float x3 = vs.w + vd.w; x3 = (x3 > 0.f) ? x3 : NEG * x3;
        if (k < CAP) *(f32x4*)&e_lds[nd][k][0] = (f32x4){x0, x1, x2, x3};
        m0 = fmaxf(m0, x0); m1 = fmaxf(m1, x1);
        m2 = fmaxf(m2, x2); m3 = fmaxf(m3, x3);
    }
    #pragma unroll
    for (int o = 1; o < 64; o <<= 1) {
        m0 = fmaxf(m0, __shfl_xor(m0, o));
        m1 = fmaxf(m1, __shfl_xor(m1, o));
        m2 = fmaxf(m2, __shfl_xor(m2, o));
        m3 = fmaxf(m3, __shfl_xor(m3, o));
    }
    // sweep 2: e = exp(x-m) -> LDS, track sum
    float t0 = 0.f, t1 = 0.f, t2 = 0.f, t3 = 0.f;
    for (int k = lane; k < deg; k += 64) {
        float x0, x1, x2, x3;
        if (k < CAP) {
            f32x4 v = *(const f32x4*)&e_lds[nd][k][0];
            x0 = v.x; x1 = v.y; x2 = v.z; x3 = v.w;
        } else {
            int s = ssorted[base + k];
            float4 vs = *(const float4*)(ssrc + (long)s * 4);
            x0 = vs.x + vd.x; x0 = (x0 > 0.f) ? x0 : NEG * x0;
            x1 = vs.y + vd.y; x1 = (x1 > 0.f) ? x1 : NEG * x1;
            x2 = vs.z + vd.z; x2 = (x2 > 0.f) ? x2 : NEG * x2;
            x3 = vs.w + vd.w; x3 = (x3 > 0.f) ? x3 : NEG * x3;
        }
        float e0 = __expf(x0 - m0), e1 = __expf(x1 - m1);
        float e2 = __expf(x2 - m2), e3 = __expf(x3 - m3);
        if (k < CAP) *(f32x4*)&e_lds[nd][k][0] = (f32x4){e0, e1, e2, e3};
        t0 += e0; t1 += e1; t2 += e2; t3 += e3;
    }
    #pragma unroll
    for (int o = 1; o < 64; o <<= 1) {
        t0 += __shfl_xor(t0, o); t1 += __shfl_xor(t1, o);
        t2 += __shfl_xor(t2, o); t3 += __shfl_xor(t3, o);
    }
    const float i0 = 1.f / (t0 + 1e-9f);
    const float i1 = 1.f / (t1 + 1e-9f);
    const float i2 = 1.f / (t2 + 1e-9f);
    const float i3 = 1.f / (t3 + 1e-9f);
    // sweep 3: write normalized alphas (coalesced float4 per edge)
    for (int k = lane; k < deg; k += 64) {
        f32x4 e;
        if (k < CAP) e = *(const f32x4*)&e_lds[nd][k][0];
        else {
            int s = ssorted[base + k];
            float4 vs = *(const float4*)(ssrc + (long)s * 4);
            float x0 = vs.x + vd.x; x0 = (x0 > 0.f) ? x0 : NEG * x0;
            float x1 = vs.y + vd.y; x1 = (x1 > 0.f) ? x1 : NEG * x1;
            float x2 = vs.z + vd.z; x2 = (x2 > 0.f) ? x2 : NEG * x2;
            float x3 = vs.w + vd.w; x3 = (x3 > 0.f) ? x3 : NEG * x3;
            e = (f32x4){__expf(x0 - m0), __expf(x1 - m1), __expf(x2 - m2), __expf(x3 - m3)};
        }
        e.x *= i0; e.y *= i1; e.z *= i2; e.w *= i3;
        *(f32x4*)(alphaN + (long)(base + k) * 4) = e;
    }
}

// ------------- agg1: feature-sliced gather (slice -> XCD), bias+ELU fused -------------
// grid = chunks*8; slice = blockIdx&7 (round-robins to XCDs). Wave per node;
// 16 edges parallel x 4 lanes x float4 = 16-feature slice.
__global__ __launch_bounds__(256) void agg1_kernel(
        const int* __restrict__ off, const int* __restrict__ ssorted,
        const float* __restrict__ alphaN, const float* __restrict__ H,
        const float* __restrict__ b, float* __restrict__ O) {
    const int slice = blockIdx.x & 7;
    const int chunk = blockIdx.x >> 3;
    const int n = chunk * 4 + (threadIdx.x >> 6);
    if (n >= NN) return;
    const int lane = threadIdx.x & 63;
    const int eg = lane >> 2, f = lane & 3;
    const int base = off[n];
    const int deg  = off[n + 1] - base;
    const int head = slice >> 1;
    const int c0 = slice * 16 + f * 4;
    f32x4 acc = (f32x4)(0.f);
    for (int k = eg; k < deg; k += 16) {
        int p = base + k;
        int s = ssorted[p];
        float a = alphaN[(long)p * 4 + head];
        f32x4 hv = *(const f32x4*)(H + (long)s * F1 + c0);
        acc += (f32x4)(a) * hv;
    }
    #pragma unroll
    for (int o = 4; o < 64; o <<= 1) {
        acc.x += __shfl_xor(acc.x, o);
        acc.y += __shfl_xor(acc.y, o);
        acc.z += __shfl_xor(acc.z, o);
        acc.w += __shfl_xor(acc.w, o);
    }
    if (eg == 0) {
        f32x4 bb = *(const f32x4*)(b + c0);
        f32x4 v = acc + bb;
        v.x = (v.x > 0.f) ? v.x : expm1f(v.x);
        v.y = (v.y > 0.f) ? v.y : expm1f(v.y);
        v.z = (v.z > 0.f) ? v.z : expm1f(v.z);
        v.w = (v.w > 0.f) ? v.w : expm1f(v.w);
        *(f32x4*)(O + (long)n * F1 + c0) = v;
    }
}

// ------------- alpha2: per-node softmax -> normalized alphas [ET] -------------
__global__ __launch_bounds__(256) void alpha2_kernel(
        const int* __restrict__ off, const int* __restrict__ ssorted,
        const float* __restrict__ ssrc, const float* __restrict__ sdst,
        float* __restrict__ alphaN2) {
    __shared__ float e_lds[4][CAP];
    const int nd = threadIdx.x >> 6;
    int n = blockIdx.x * 4 + nd;
    if (n >= NN) return;
    const int lane = threadIdx.x & 63;
    const int base = off[n];
    const int deg  = off[n + 1] - base;
    const float sdn = sdst[n];

    float m = -1e30f;
    for (int k = lane; k < deg; k += 64) {
        int s = ssorted[base + k];
        float x = ssrc[s] + sdn;
        x = (x > 0.f) ? x : NEG * x;
        if (k < CAP) e_lds[nd][k] = x;
        m = fmaxf(m, x);
    }
    #pragma unroll
    for (int o = 1; o < 64; o <<= 1) m = fmaxf(m, __shfl_xor(m, o));
    float t = 0.f;
    for (int k = lane; k < deg; k += 64) {
        float x;
        if (k < CAP) x = e_lds[nd][k];
        else {
            int s = ssorted[base + k];
            x = ssrc[s] + sdn;
            x = (x > 0.f) ? x : NEG * x;
        }
        float e = __expf(x - m);
        if (k < CAP) e_lds[nd][k] = e;
        t += e;
    }
    #pragma unroll
    for (int o = 1; o < 64; o <<= 1) t += __shfl_xor(t, o);
    const float inv = 1.f / (t + 1e-9f);
    for (int k = lane; k < deg; k += 64) {
        float e;
        if (k < CAP) e = e_lds[nd][k];
        else {
            int s = ssorted[base + k];
            float x = ssrc[s] + sdn;
            x = (x > 0.f) ? x : NEG * x;
            e = __expf(x - m);
        }
        alphaN2[base + k] = e * inv;
    }
}

// ------------- agg2: class-sliced gather (slice -> XCD), bias fused -------------
// 8 slices x 5 classes. Wave per node; lanes = edges.
__global__ __launch_bounds__(256) void agg2_kernel(
        const int* __restrict__ off, const int* __restrict__ ssorted,
        const float* __restrict__ alphaN2, const float* __restrict__ Z,
        const float* __restrict__ b, float* __restrict__ O2) {
    const int slice = blockIdx.x & 7;
    const int chunk = blockIdx.x >> 3;
    const int n = chunk * 4 + (threadIdx.x >> 6);
    if (n >= NN) return;
    const int lane = threadIdx.x & 63;
    const int base = off[n];
    const int deg  = off[n + 1] - base;
    const int c0 = slice * 5;
    float a0 = 0.f, a1 = 0.f, a2 = 0.f, a3 = 0.f, a4 = 0.f;
    for (int k = lane; k < deg; k += 64) {
        int p = base + k;
        int s = ssorted[p];
        float a = alphaN2[p];
        const float* zp = Z + (long)s * NC + c0;
        a0 += a * zp[0]; a1 += a * zp[1]; a2 += a * zp[2];
        a3 += a * zp[3]; a4 += a * zp[4];
    }
    #pragma unroll
    for (int o = 1; o < 64; o <<= 1) {
        a0 += __shfl_xor(a0, o); a1 += __shfl_xor(a1, o);
        a2 += __shfl_xor(a2, o); a3 += __shfl_xor(a3, o);
        a4 += __shfl_xor(a4, o);
    }
    if (lane == 0) {
        float* op = O2 + (long)n * NC + c0;
        op[0] = a0 + b[c0 + 0];
        op[1] = a1 + b[c0 + 1];
        op[2] = a2 + b[c0 + 2];
        op[3] = a3 + b[c0 + 3];
        op[4] = a4 + b[c0 + 4];
    }
}

// ------------- final row softmax (bias already applied) -------------
__global__ __launch_bounds__(256) void softmax_kernel(const float* __restrict__ O2,
        float* __restrict__ out) {
    long gt = (long)blockIdx.x * blockDim.x + threadIdx.x;
    long n = gt >> 6;
    int lane = threadIdx.x & 63;
    if (n >= NN) return;
    float v = (lane < NC) ? O2[n * NC + lane] : -1e30f;
    float mx = v;
    #pragma unroll
    for (int o = 32; o > 0; o >>= 1) mx = fmaxf(mx, __shfl_xor(mx, o));
    float e = (lane < NC) ? __expf(v - mx) : 0.f;
    float sum = e;
    #pragma unroll
    for (int o = 32; o > 0; o >>= 1) sum += __shfl_xor(sum, o);
    if (lane < NC) out[n * NC + lane] = e / sum;
}

extern "C" void kernel_launch(void* const* d_in, const int* in_sizes, int n_in,
                              void* d_out, int out_size, void* d_ws, size_t ws_size,
                              hipStream_t stream) {
    const float* x      = (const float*)d_in[0];
    const int*   src    = (const int*)  d_in[1];
    const int*   dst    = (const int*)  d_in[2];
    const float* W1     = (const float*)d_in[3];
    const float* a_src1 = (const float*)d_in[4];
    const float* a_dst1 = (const float*)d_in[5];
    const float* b1     = (const float*)d_in[6];
    const float* W2     = (const float*)d_in[7];
    const float* a_src2 = (const float*)d_in[8];
    const float* a_dst2 = (const float*)d_in[9];
    const float* b2     = (const float*)d_in[10];
    float* out = (float*)d_out;

    float* ws   = (float*)d_ws;
    float* hpre = ws;                   // 6,400,000 (reused as out2 after agg1)
    float* s1s  = hpre + 6400000;       //   200,000
    float* s1d  = s1s + 200000;         //   200,000
    float* h1   = s1d + 200000;         // 6,400,000
    float* z2   = h1 + 6400000;         // 2,000,000
    float* s2s  = z2 + 2000000;         //    50,000
    float* s2d  = s2s + 50000;          //    50,000
    float* alphaN1 = s2d + 50000;       // 3,400,000 (reused as alphaN2)
    float* out2    = hpre;              // aliases hpre (dead after agg1)
    float* alphaN2 = alphaN1;           // aliases alphaN1 (dead after agg1)
    int*   deg     = (int*)(alphaN1 + 3400000);  //  50,000
    int*   off     = deg + 50000;           //  50,008 (padded)
    int*   cur     = off + 50008;           //  50,000
    int*   ssorted = cur + 50000;           // 850,000
    int*   bsum    = ssorted + 850000;      //     256
    int*   bbase   = bsum + 256;            //     256
    unsigned short* Wh1T = (unsigned short*)(bbase + 256);      // 65,536
    unsigned short* Wl1T = Wh1T + 65536;                        // 65,536
    unsigned short* Wh2T = Wl1T + 65536;                        //  6,144
    unsigned short* Wl2T = Wh2T + 6144;                         //  6,144

    // prep: zero deg + weight splits
    prep_kernel<<<(DIN * F1 + 255) / 256, 256, 0, stream>>>(W1, W2, deg, Wh1T, Wl1T, Wh2T, Wl2T);

    // CSR build (by dst): hist -> hierarchical scan -> scatter
    hist_kernel<<<(ET + 255) / 256, 256, 0, stream>>>(dst, deg);
    partial_kernel<<<SCAN_NB, 256, 0, stream>>>(deg, bsum);
    scanp_kernel<<<1, 256, 0, stream>>>(bsum, bbase);
    emit_kernel<<<SCAN_NB, 256, 0, stream>>>(deg, bbase, off, cur);
    scatter_kernel<<<(ET + 255) / 256, 256, 0, stream>>>(src, dst, cur, ssorted);

    // layer 1
    gemm1_mfma<<<(NN + 63) / 64, 256, 0, stream>>>(x, Wh1T, Wl1T, a_src1, a_dst1, hpre, s1s, s1d);
    alpha1_kernel<<<(NN + 3) / 4, 256, 0, stream>>>(off, ssorted, s1s, s1d, alphaN1);
    agg1_kernel<<<((NN + 3) / 4) * 8, 256, 0, stream>>>(off, ssorted, alphaN1, hpre, b1, h1);

    // layer 2
    gemm2_mfma<<<(NN + 63) / 64, 256, 0, stream>>>(h1, Wh2T, Wl2T, a_src2, a_dst2, z2, s2s, s2d);
    alpha2_kernel<<<(NN + 3) / 4, 256, 0, stream>>>(off, ssorted, s2s, s2d, alphaN2);
    agg2_kernel<<<((NN + 3) / 4) * 8, 256, 0, stream>>>(off, ssorted, alphaN2, z2, b2, out2);
    softmax_kernel<<<(int)(((long)NN * 64 + 255) / 256), 256, 0, stream>>>(out2, out);
}

// Round 8
// 401.152 us; speedup vs baseline: 1.5243x; 1.5243x over previous
//
#include <hip/hip_runtime.h>
#include <hip/hip_bf16.h>
#include <math.h>

// GAT 2-layer, MI355X. CSR aggregation (LDS-cached alphas, edge-group-parallel
// gather for MLP) + MFMA GEMMs (3-term bf16 split ~ f32 accuracy).
#define NN 50000
#define NE 800000
#define ET 850000          // NE + NN self loops
#define DIN 512
#define F1 128             // HEADS*HIDDEN
#define NC 40
#define NEG 0.2f
#define CAP 128            // per-node cached-edge cap (max degree ~50 stat.)
#define SCAN_NB ((NN + 255) / 256)   // 196

typedef __attribute__((ext_vector_type(8))) short s16x8;
typedef __attribute__((ext_vector_type(4))) float f32x4;

__device__ inline unsigned short bfh(float f) {
    __hip_bfloat16 h = __float2bfloat16(f);
    return __builtin_bit_cast(unsigned short, h);
}
__device__ inline float bff(unsigned short u) {
    unsigned int x = (unsigned int)u << 16;
    return __builtin_bit_cast(float, x);
}

__device__ inline void split8(f32x4 v0, f32x4 v1, s16x8* hi, s16x8* lo) {
    float f[8] = {v0.x, v0.y, v0.z, v0.w, v1.x, v1.y, v1.z, v1.w};
    #pragma unroll
    for (int j = 0; j < 8; ++j) {
        unsigned short h = bfh(f[j]);
        (*hi)[j] = (short)h;
        (*lo)[j] = (short)bfh(f[j] - bff(h));
    }
}

__device__ inline void gl16(const void* g, void* l) {
    __builtin_amdgcn_global_load_lds((const __attribute__((address_space(1))) unsigned int*)g,
                                     (__attribute__((address_space(3))) unsigned int*)l, 16, 0, 0);
}

// ---------------- prep: zero deg + weight splits (merged) ----------------
__global__ void prep_kernel(const float* __restrict__ W1,
        const float* __restrict__ W2, int* __restrict__ deg,
        unsigned short* __restrict__ Wh1T, unsigned short* __restrict__ Wl1T,
        unsigned short* __restrict__ Wh2T, unsigned short* __restrict__ Wl2T) {
    int i = blockIdx.x * blockDim.x + threadIdx.x;
    if (i < NN) deg[i] = 0;
    if (i < DIN * F1) {
        int k = i >> 7, c = i & 127;
        float w = W1[i];
        unsigned short h = bfh(w);
        unsigned short l = bfh(w - bff(h));
        Wh1T[c * DIN + k] = h;
        Wl1T[c * DIN + k] = l;
    }
    if (i < 48 * 128) {
        int c = i >> 7, k = i & 127;
        float w = (c < NC) ? W2[k * NC + c] : 0.f;
        unsigned short h = bfh(w);
        unsigned short l = bfh(w - bff(h));
        Wh2T[c * 128 + k] = h;
        Wl2T[c * 128 + k] = l;
    }
}

// ---------------- CSR build ----------------
__global__ void hist_kernel(const int* __restrict__ dst, int* __restrict__ deg) {
    int e = blockIdx.x * blockDim.x + threadIdx.x;
    if (e >= ET) return;
    int d = (e < NE) ? dst[e] : (e - NE);
    atomicAdd(&deg[d], 1);
}

__global__ __launch_bounds__(256) void partial_kernel(const int* __restrict__ deg,
        int* __restrict__ bsum) {
    __shared__ int red[4];
    int i = blockIdx.x * 256 + threadIdx.x;
    int v = (i < NN) ? deg[i] : 0;
    #pragma unroll
    for (int o = 1; o < 64; o <<= 1) v += __shfl_xor(v, o);
    if ((threadIdx.x & 63) == 0) red[threadIdx.x >> 6] = v;
    __syncthreads();
    if (threadIdx.x == 0) bsum[blockIdx.x] = red[0] + red[1] + red[2] + red[3];
}

__global__ __launch_bounds__(256) void scanp_kernel(const int* __restrict__ bsum,
        int* __restrict__ bbase) {
    __shared__ int s[256];
    int t = threadIdx.x;
    s[t] = (t < SCAN_NB) ? bsum[t] : 0;
    __syncthreads();
    #pragma unroll
    for (int o = 1; o < 256; o <<= 1) {
        int v = (t >= o) ? s[t - o] : 0;
        __syncthreads();
        s[t] += v;
        __syncthreads();
    }
    if (t < SCAN_NB) bbase[t] = (t == 0) ? 0 : s[t - 1];
}

__global__ __launch_bounds__(256) void emit_kernel(const int* __restrict__ deg,
        const int* __restrict__ bbase, int* __restrict__ off, int* __restrict__ cur) {
    __shared__ int s[256];
    int t = threadIdx.x;
    int i = blockIdx.x * 256 + t;
    int d = (i < NN) ? deg[i] : 0;
    s[t] = d;
    __syncthreads();
    #pragma unroll
    for (int o = 1; o < 256; o <<= 1) {
        int v = (t >= o) ? s[t - o] : 0;
        __syncthreads();
        s[t] += v;
        __syncthreads();
    }
    int o0 = bbase[blockIdx.x] + s[t] - d;   // exclusive
    if (i < NN) { off[i] = o0; cur[i] = o0; }
    if (i == NN - 1) off[NN] = o0 + d;
}

__global__ void scatter_kernel(const int* __restrict__ src, const int* __restrict__ dst,
        int* __restrict__ cur, int* __restrict__ ssorted) {
    int e = blockIdx.x * blockDim.x + threadIdx.x;
    if (e >= ET) return;
    int s = (e < NE) ? src[e] : (e - NE);
    int d = (e < NE) ? dst[e] : (e - NE);
    int pos = atomicAdd(&cur[d], 1);
    ssorted[pos] = s;
}

// ---------------- GEMM1 MFMA: [NN,512] x [512,128] -> hpre, + fused scores ----------------
__global__ __launch_bounds__(256) void gemm1_mfma(const float* __restrict__ X,
        const unsigned short* __restrict__ BhT, const unsigned short* __restrict__ BlT,
        const float* __restrict__ a_src, const float* __restrict__ a_dst,
        float* __restrict__ H, float* __restrict__ s1s, float* __restrict__ s1d) {
    __shared__ char lds[49152];               // Ah 8K | Al 8K | Bh 16K | Bl 16K
    char* ldsAh = lds;
    char* ldsAl = lds + 8192;
    char* ldsBh = lds + 16384;
    char* ldsBl = lds + 32768;
    const int tid = threadIdx.x;
    const int wid = tid >> 6, lane = tid & 63;
    const int wm = wid >> 1, wn = wid & 1;
    const int l15 = lane & 15, lg = lane >> 4;
    const int row0 = blockIdx.x * 64;

    const int arow = tid >> 2;
    const int akc  = (tid & 3) * 16;
    const int asw  = (arow & 7) << 4;
    int agr = row0 + arow; if (agr > NN - 1) agr = NN - 1;
    const float* aptr = X + (long)agr * DIN + akc;

    f32x4 acc[2][4];
    #pragma unroll
    for (int mi = 0; mi < 2; ++mi)
        #pragma unroll
        for (int ni = 0; ni < 4; ++ni) acc[mi][ni] = (f32x4)(0.f);

    for (int k0 = 0; k0 < DIN; k0 += 64) {
        #pragma unroll
        for (int p = 0; p < 4; ++p) {
            int q = p * 256 + tid;
            int dstoff = (p * 256 + wid * 64) << 4;
            int rr = q >> 3;
            int w = (q & 7) << 4;
            int sw = (rr & 7) << 4;
            long sb = (long)rr * (DIN * 2) + k0 * 2 + (w ^ sw);
            gl16((const char*)BhT + sb, ldsBh + dstoff);
            gl16((const char*)BlT + sb, ldsBl + dstoff);
        }
        {
            f32x4 v0 = *(const f32x4*)(aptr + k0);
            f32x4 v1 = *(const f32x4*)(aptr + k0 + 4);
            f32x4 v2 = *(const f32x4*)(aptr + k0 + 8);
            f32x4 v3 = *(const f32x4*)(aptr + k0 + 12);
            s16x8 h0, l0, h1, l1;
            split8(v0, v1, &h0, &l0);
            split8(v2, v3, &h1, &l1);
            int b0 = arow * 128 + ((akc * 2) ^ asw);
            int b1 = arow * 128 + ((akc * 2 + 16) ^ asw);
            *(s16x8*)(ldsAh + b0) = h0;
            *(s16x8*)(ldsAh + b1) = h1;
            *(s16x8*)(ldsAl + b0) = l0;
            *(s16x8*)(ldsAl + b1) = l1;
        }
        __syncthreads();
        #pragma unroll
        for (int ks = 0; ks < 2; ++ks) {
            s16x8 ah[2], al[2], bh[4], bl[4];
            #pragma unroll
            for (int mi = 0; mi < 2; ++mi) {
                int row = wm * 32 + mi * 16 + l15;
                int sw = (row & 7) << 4;
                int kb = (ks * 32 + lg * 8) * 2;
                ah[mi] = *(const s16x8*)(ldsAh + row * 128 + (kb ^ sw));
                al[mi] = *(const s16x8*)(ldsAl + row * 128 + (kb ^ sw));
            }
            #pragma unroll
            for (int ni = 0; ni < 4; ++ni) {
                int col = wn * 64 + ni * 16 + l15;
                int sw = (col & 7) << 4;
                int kb = (ks * 32 + lg * 8) * 2;
                bh[ni] = *(const s16x8*)(ldsBh + col * 128 + (kb ^ sw));
                bl[ni] = *(const s16x8*)(ldsBl + col * 128 + (kb ^ sw));
            }
            #pragma unroll
            for (int mi = 0; mi < 2; ++mi)
                #pragma unroll
                for (int ni = 0; ni < 4; ++ni) {
                    acc[mi][ni] = __builtin_amdgcn_mfma_f32_16x16x32_bf16(ah[mi], bh[ni], acc[mi][ni], 0, 0, 0);
                    acc[mi][ni] = __builtin_amdgcn_mfma_f32_16x16x32_bf16(ah[mi], bl[ni], acc[mi][ni], 0, 0, 0);
                    acc[mi][ni] = __builtin_amdgcn_mfma_f32_16x16x32_bf16(al[mi], bh[ni], acc[mi][ni], 0, 0, 0);
                }
        }
        __syncthreads();
    }

    #pragma unroll
    for (int mi = 0; mi < 2; ++mi)
        #pragma unroll
        for (int ni = 0; ni < 4; ++ni) {
            int col = wn * 64 + ni * 16 + l15;
            #pragma unroll
            for (int r = 0; r < 4; ++r) {
                int grow = row0 + wm * 32 + mi * 16 + lg * 4 + r;
                if (grow < NN) H[(long)grow * F1 + col] = acc[mi][ni][r];
            }
        }
    float av[4], bv[4];
    #pragma unroll
    for (int ni = 0; ni < 4; ++ni) {
        int col = wn * 64 + ni * 16 + l15;
        av[ni] = a_src[col];
        bv[ni] = a_dst[col];
    }
    #pragma unroll
    for (int mi = 0; mi < 2; ++mi)
        #pragma unroll
        for (int hl = 0; hl < 2; ++hl) {
            #pragma unroll
            for (int r = 0; r < 4; ++r) {
                float t1 = acc[mi][2 * hl][r] * av[2 * hl] + acc[mi][2 * hl + 1][r] * av[2 * hl + 1];
                float t2 = acc[mi][2 * hl][r] * bv[2 * hl] + acc[mi][2 * hl + 1][r] * bv[2 * hl + 1];
                #pragma unroll
                for (int o = 1; o < 16; o <<= 1) {
                    t1 += __shfl_xor(t1, o);
                    t2 += __shfl_xor(t2, o);
                }
                int grow = row0 + wm * 32 + mi * 16 + lg * 4 + r;
                if (l15 == 0 && grow < NN) {
                    int head = 2 * wn + hl;
                    s1s[grow * 4 + head] = t1;
                    s1d[grow * 4 + head] = t2;
                }
            }
        }
}

// ---------------- GEMM2 MFMA: [NN,128] x [128,40->48] -> Z, + fused scores ----------------
__global__ __launch_bounds__(256) void gemm2_mfma(const float* __restrict__ H1,
        const unsigned short* __restrict__ B2h, const unsigned short* __restrict__ B2l,
        const float* __restrict__ a_src, const float* __restrict__ a_dst,
        float* __restrict__ Z, float* __restrict__ s2s, float* __restrict__ s2d) {
    __shared__ char lds[57344];               // A 32K | Bh 12K | Bl 12K
    char* ldsA  = lds;
    char* ldsBh = lds + 32768;
    char* ldsBl = lds + 45056;
    const int tid = threadIdx.x;
    const int wid = tid >> 6, lane = tid & 63;
    const int l15 = lane & 15, lg = lane >> 4;
    const int row0 = blockIdx.x * 64;

    #pragma unroll
    for (int p = 0; p < 8; ++p) {
        int q = p * 256 + tid;
        int row = q >> 5;
        int w = (q & 31) << 4;
        int sw = (row & 7) << 4;
        int gr = row0 + row; if (gr > NN - 1) gr = NN - 1;
        gl16((const char*)(H1 + (long)gr * F1) + (w ^ sw), ldsA + ((p * 256 + wid * 64) << 4));
    }
    #pragma unroll
    for (int p = 0; p < 3; ++p) {
        int q = p * 256 + tid;
        int rr = q >> 4;
        int w = (q & 15) << 4;
        int sw = (rr & 7) << 4;
        int dstoff = (p * 256 + wid * 64) << 4;
        gl16((const char*)B2h + rr * 256 + (w ^ sw), ldsBh + dstoff);
        gl16((const char*)B2l + rr * 256 + (w ^ sw), ldsBl + dstoff);
    }
    __syncthreads();

    f32x4 acc[3];
    #pragma unroll
    for (int ni = 0; ni < 3; ++ni) acc[ni] = (f32x4)(0.f);

    #pragma unroll
    for (int ks = 0; ks < 4; ++ks) {
        int row = wid * 16 + l15;
        int sw = (row & 7) << 4;
        int kb = (ks * 32 + lg * 8) * 4;
        f32x4 v0 = *(const f32x4*)(ldsA + row * 512 + ((kb)      ^ sw));
        f32x4 v1 = *(const f32x4*)(ldsA + row * 512 + ((kb + 16) ^ sw));
        s16x8 ah, al;
        split8(v0, v1, &ah, &al);
        #pragma unroll
        for (int ni = 0; ni < 3; ++ni) {
            int cc = ni * 16 + l15;
            int swb = (cc & 7) << 4;
            int kb2 = (ks * 32 + lg * 8) * 2;
            s16x8 bh = *(const s16x8*)(ldsBh + cc * 256 + (kb2 ^ swb));
            s16x8 bl = *(const s16x8*)(ldsBl + cc * 256 + (kb2 ^ swb));
            acc[ni] = __builtin_amdgcn_mfma_f32_16x16x32_bf16(ah, bh, acc[ni], 0, 0, 0);
            acc[ni] = __builtin_amdgcn_mfma_f32_16x16x32_bf16(ah, bl, acc[ni], 0, 0, 0);
            acc[ni] = __builtin_amdgcn_mfma_f32_16x16x32_bf16(al, bh, acc[ni], 0, 0, 0);
        }
    }

    float av[3], bv[3];
    #pragma unroll
    for (int ni = 0; ni < 3; ++ni) {
        int cc = ni * 16 + l15;
        av[ni] = (cc < NC) ? a_src[cc] : 0.f;
        bv[ni] = (cc < NC) ? a_dst[cc] : 0.f;
    }
    #pragma unroll
    for (int r = 0; r < 4; ++r) {
        int grow = row0 + wid * 16 + lg * 4 + r;
        bool ok = grow < NN;
        float t1 = acc[0][r] * av[0] + acc[1][r] * av[1] + acc[2][r] * av[2];
        float t2 = acc[0][r] * bv[0] + acc[1][r] * bv[1] + acc[2][r] * bv[2];
        #pragma unroll
        for (int o = 1; o < 16; o <<= 1) {
            t1 += __shfl_xor(t1, o);
            t2 += __shfl_xor(t2, o);
        }
        #pragma unroll
        for (int ni = 0; ni < 3; ++ni) {
            int cc = ni * 16 + l15;
            if (ok && cc < NC) Z[(long)grow * NC + cc] = acc[ni][r];
        }
        if (ok && l15 == 0) { s2s[grow] = t1; s2d[grow] = t2; }
    }
}

// ------------- fused layer-1 softmax + aggregate + bias + ELU -------------
// wave per dst node. pass 1: edges parallel over 64 lanes (softmax stats + LDS
// cache). pass 2: 4 edge-groups x 16 lanes x 8 feats -> 4+ gathers in flight.
__global__ __launch_bounds__(256) void fusedagg1_kernel(
        const int* __restrict__ off, const int* __restrict__ ssorted,
        const float* __restrict__ ssrc, const float* __restrict__ sdst,
        const float* __restrict__ H, const float* __restrict__ b,
        float* __restrict__ O) {
    __shared__ int idx_lds[4][CAP];
    __shared__ __align__(16) float e_lds[4][CAP][4];
    const int nd = threadIdx.x >> 6;
    int n = blockIdx.x * 4 + nd;
    if (n >= NN) return;
    const int lane = threadIdx.x & 63;
    const int base = off[n];
    const int deg  = off[n + 1] - base;
    const float4 vd = *(const float4*)(sdst + (long)n * 4);

    // pass 1a: logits -> LDS, track max
    float m0 = -1e30f, m1 = -1e30f, m2 = -1e30f, m3 = -1e30f;
    for (int k = lane; k < deg; k += 64) {
        int s = ssorted[base + k];
        float4 vs = *(const float4*)(ssrc + (long)s * 4);
        float x0 = vs.x + vd.x; x0 = (x0 > 0.f) ? x0 : NEG * x0;
        float x1 = vs.y + vd.y; x1 = (x1 > 0.f) ? x1 : NEG * x1;
        float x2 = vs.z + vd.z; x2 = (x2 > 0.f) ? x2 : NEG * x2;
        float x3 = vs.w + vd.w; x3 = (x3 > 0.f) ? x3 : NEG * x3;
        if (k < CAP) {
            idx_lds[nd][k] = s;
            *(f32x4*)&e_lds[nd][k][0] = (f32x4){x0, x1, x2, x3};
        }
        m0 = fmaxf(m0, x0); m1 = fmaxf(m1, x1);
        m2 = fmaxf(m2, x2); m3 = fmaxf(m3, x3);
    }
    #pragma unroll
    for (int o = 1; o < 64; o <<= 1) {
        m0 = fmaxf(m0, __shfl_xor(m0, o));
        m1 = fmaxf(m1, __shfl_xor(m1, o));
        m2 = fmaxf(m2, __shfl_xor(m2, o));
        m3 = fmaxf(m3, __shfl_xor(m3, o));
    }
    // pass 1b: e = exp(x-m) -> LDS, track sum
    float t0 = 0.f, t1 = 0.f, t2 = 0.f, t3 = 0.f;
    for (int k = lane; k < deg; k += 64) {
        float x0, x1, x2, x3;
        if (k < CAP) {
            f32x4 v = *(const f32x4*)&e_lds[nd][k][0];
            x0 = v.x; x1 = v.y; x2 = v.z; x3 = v.w;
        } else {
            int s = ssorted[base + k];
            float4 vs = *(const float4*)(ssrc + (long)s * 4);
            x0 = vs.x + vd.x; x0 = (x0 > 0.f) ? x0 : NEG * x0;
            x1 = vs.y + vd.y; x1 = (x1 > 0.f) ? x1 : NEG * x1;
            x2 = vs.z + vd.z; x2 = (x2 > 0.f) ? x2 : NEG * x2;
            x3 = vs.w + vd.w; x3 = (x3 > 0.f) ? x3 : NEG * x3;
        }
        float e0 = __expf(x0 - m0), e1 = __expf(x1 - m1);
        float e2 = __expf(x2 - m2), e3 = __expf(x3 - m3);
        if (k < CAP) *(f32x4*)&e_lds[nd][k][0] = (f32x4){e0, e1, e2, e3};
        t0 += e0; t1 += e1; t2 += e2; t3 += e3;
    }
    #pragma unroll
    for (int o = 1; o < 64; o <<= 1) {
        t0 += __shfl_xor(t0, o); t1 += __shfl_xor(t1, o);
        t2 += __shfl_xor(t2, o); t3 += __shfl_xor(t3, o);
    }
    // pass 2: edge-grouped gather. lane = g*16 + l; feats [8l, 8l+8), head=l>>2.
    const int g = lane >> 4;
    const int l = lane & 15;
    const int hd = l >> 2;
    const float mh  = (hd == 0) ? m0 : (hd == 1) ? m1 : (hd == 2) ? m2 : m3;
    const float th  = (hd == 0) ? t0 : (hd == 1) ? t1 : (hd == 2) ? t2 : t3;
    const float ih  = 1.f / (th + 1e-9f);
    const float vdh = (hd == 0) ? vd.x : (hd == 1) ? vd.y : (hd == 2) ? vd.z : vd.w;
    const int c0 = l * 8;
    f32x4 accA = (f32x4)(0.f), accB = (f32x4)(0.f);
    const int kend = (deg < CAP) ? deg : CAP;
    for (int k = g; k < kend; k += 4) {
        int s = idx_lds[nd][k];
        float e = e_lds[nd][k][hd];
        const float* hp = H + (long)s * F1 + c0;
        f32x4 h0 = *(const f32x4*)(hp);
        f32x4 h1 = *(const f32x4*)(hp + 4);
        accA += (f32x4)(e) * h0;
        accB += (f32x4)(e) * h1;
    }
    for (int k = CAP + g; k < deg; k += 4) {   // statistically never taken
        int s = ssorted[base + k];
        float4 vs = *(const float4*)(ssrc + (long)s * 4);
        float x = ((hd == 0) ? vs.x : (hd == 1) ? vs.y : (hd == 2) ? vs.z : vs.w) + vdh;
        x = (x > 0.f) ? x : NEG * x;
        float e = __expf(x - mh);
        const float* hp = H + (long)s * F1 + c0;
        f32x4 h0 = *(const f32x4*)(hp);
        f32x4 h1 = *(const f32x4*)(hp + 4);
        accA += (f32x4)(e) * h0;
        accB += (f32x4)(e) * h1;
    }
    // reduce across the 4 edge-groups
    #pragma unroll
    for (int o = 16; o < 64; o <<= 1) {
        accA.x += __shfl_xor(accA.x, o); accA.y += __shfl_xor(accA.y, o);
        accA.z += __shfl_xor(accA.z, o); accA.w += __shfl_xor(accA.w, o);
        accB.x += __shfl_xor(accB.x, o); accB.y += __shfl_xor(accB.y, o);
        accB.z += __shfl_xor(accB.z, o); accB.w += __shfl_xor(accB.w, o);
    }
    if (g == 0) {
        f32x4 bbA = *(const f32x4*)(b + c0);
        f32x4 bbB = *(const f32x4*)(b + c0 + 4);
        f32x4 vA = accA * (f32x4)(ih) + bbA;
        f32x4 vB = accB * (f32x4)(ih) + bbB;
        vA.x = (vA.x > 0.f) ? vA.x : expm1f(vA.x);
        vA.y = (vA.y > 0.f) ? vA.y : expm1f(vA.y);
        vA.z = (vA.z > 0.f) ? vA.z : expm1f(vA.z);
        vA.w = (vA.w > 0.f) ? vA.w : expm1f(vA.w);
        vB.x = (vB.x > 0.f) ? vB.x : expm1f(vB.x);
        vB.y = (vB.y > 0.f) ? vB.y : expm1f(vB.y);
        vB.z = (vB.z > 0.f) ? vB.z : expm1f(vB.z);
        vB.w = (vB.w > 0.f) ? vB.w : expm1f(vB.w);
        *(f32x4*)(O + (long)n * F1 + c0)     = vA;
        *(f32x4*)(O + (long)n * F1 + c0 + 4) = vB;
    }
}

// ------------- fused layer-2 softmax + aggregate + bias + row softmax -------------
// pass 2: 8 edge-groups x 8 lanes x 5 classes -> 8 gathers in flight.
__global__ __launch_bounds__(256) void fusedagg2_kernel(
        const int* __restrict__ off, const int* __restrict__ ssorted,
        const float* __restrict__ ssrc, const float* __restrict__ sdst,
        const float* __restrict__ Z, const float* __restrict__ b,
        float* __restrict__ out) {
    __shared__ int   idx_lds[4][CAP];
    __shared__ float e_lds[4][CAP];
    const int nd = threadIdx.x >> 6;
    int n = blockIdx.x * 4 + nd;
    if (n >= NN) return;
    const int lane = threadIdx.x & 63;
    const int base = off[n];
    const int deg  = off[n + 1] - base;
    const float sdn = sdst[n];

    float m = -1e30f;
    for (int k = lane; k < deg; k += 64) {
        int s = ssorted[base + k];
        float x = ssrc[s] + sdn;
        x = (x > 0.f) ? x : NEG * x;
        if (k < CAP) { idx_lds[nd][k] = s; e_lds[nd][k] = x; }
        m = fmaxf(m, x);
    }
    #pragma unroll
    for (int o = 1; o < 64; o <<= 1) m = fmaxf(m, __shfl_xor(m, o));
    float t = 0.f;
    for (int k = lane; k < deg; k += 64) {
        float x;
        if (k < CAP) x = e_lds[nd][k];
        else {
            int s = ssorted[base + k];
            x = ssrc[s] + sdn;
            x = (x > 0.f) ? x : NEG * x;
        }
        float e = __expf(x - m);
        if (k < CAP) e_lds[nd][k] = e;
        t += e;
    }
    #pragma unroll
    for (int o = 1; o < 64; o <<= 1) t += __shfl_xor(t, o);
    const float inv = 1.f / (t + 1e-9f);

    // pass 2: lane = g*8 + l; classes [5l, 5l+5)
    const int g = lane >> 3;
    const int l = lane & 7;
    const int c0 = l * 5;
    float a0 = 0.f, a1 = 0.f, a2 = 0.f, a3 = 0.f, a4 = 0.f;
    const int kend = (deg < CAP) ? deg : CAP;
    for (int k = g; k < kend; k += 8) {
        int s = idx_lds[nd][k];
        float e = e_lds[nd][k];
        const float* zp = Z + (long)s * NC + c0;
        a0 += e * zp[0]; a1 += e * zp[1]; a2 += e * zp[2];
        a3 += e * zp[3]; a4 += e * zp[4];
    }
    for (int k = CAP + g; k < deg; k += 8) {   // statistically never taken
        int s = ssorted[base + k];
        float x = ssrc[s] + sdn;
        x = (x > 0.f) ? x : NEG * x;
        float e = __expf(x - m);
        const float* zp = Z + (long)s * NC + c0;
        a0 += e * zp[0]; a1 += e * zp[1]; a2 += e * zp[2];
        a3 += e * zp[3]; a4 += e * zp[4];
    }
    #pragma unroll
    for (int o = 8; o < 64; o <<= 1) {
        a0 += __shfl_xor(a0, o); a1 += __shfl_xor(a1, o);
        a2 += __shfl_xor(a2, o); a3 += __shfl_xor(a3, o);
        a4 += __shfl_xor(a4, o);
    }
    if (g == 0) {
        float v0 = a0 * inv + b[c0 + 0];
        float v1 = a1 * inv + b[c0 + 1];
        float v2 = a2 * inv + b[c0 + 2];
        float v3 = a3 * inv + b[c0 + 3];
        float v4 = a4 * inv + b[c0 + 4];
        // row softmax across lanes 0..7 (each 5 classes)
        float mx = fmaxf(fmaxf(fmaxf(v0, v1), fmaxf(v2, v3)), v4);
        #pragma unroll
        for (int o = 1; o < 8; o <<= 1) mx = fmaxf(mx, __shfl_xor(mx, o));
        float e0 = __expf(v0 - mx), e1 = __expf(v1 - mx), e2 = __expf(v2 - mx);
        float e3 = __expf(v3 - mx), e4 = __expf(v4 - mx);
        float s = e0 + e1 + e2 + e3 + e4;
        #pragma unroll
        for (int o = 1; o < 8; o <<= 1) s += __shfl_xor(s, o);
        float is = 1.f / s;
        float* op = out + (long)n * NC + c0;
        op[0] = e0 * is; op[1] = e1 * is; op[2] = e2 * is;
        op[3] = e3 * is; op[4] = e4 * is;
    }
}

extern "C" void kernel_launch(void* const* d_in, const int* in_sizes, int n_in,
                              void* d_out, int out_size, void* d_ws, size_t ws_size,
                              hipStream_t stream) {
    const float* x      = (const float*)d_in[0];
    const int*   src    = (const int*)  d_in[1];
    const int*   dst    = (const int*)  d_in[2];
    const float* W1     = (const float*)d_in[3];
    const float* a_src1 = (const float*)d_in[4];
    const float* a_dst1 = (const float*)d_in[5];
    const float* b1     = (const float*)d_in[6];
    const float* W2     = (const float*)d_in[7];
    const float* a_src2 = (const float*)d_in[8];
    const float* a_dst2 = (const float*)d_in[9];
    const float* b2     = (const float*)d_in[10];
    float* out = (float*)d_out;

    float* ws   = (float*)d_ws;
    float* hpre = ws;                   // 6,400,000
    float* s1s  = hpre + 6400000;       //   200,000
    float* s1d  = s1s + 200000;         //   200,000
    float* h1   = s1d + 200000;         // 6,400,000
    float* z2   = h1 + 6400000;         // 2,000,000
    float* s2s  = z2 + 2000000;         //    50,000
    float* s2d  = s2s + 50000;          //    50,000
    int*   deg     = (int*)(s2d + 50000);   //  50,000
    int*   off     = deg + 50000;           //  50,008 (padded)
    int*   cur     = off + 50008;           //  50,000
    int*   ssorted = cur + 50000;           // 850,000
    int*   bsum    = ssorted + 850000;      //     256
    int*   bbase   = bsum + 256;            //     256
    unsigned short* Wh1T = (unsigned short*)(bbase + 256);      // 65,536
    unsigned short* Wl1T = Wh1T + 65536;                        // 65,536
    unsigned short* Wh2T = Wl1T + 65536;                        //  6,144
    unsigned short* Wl2T = Wh2T + 6144;                         //  6,144

    // prep: zero deg + weight splits
    prep_kernel<<<(DIN * F1 + 255) / 256, 256, 0, stream>>>(W1, W2, deg, Wh1T, Wl1T, Wh2T, Wl2T);

    // CSR build (by dst): hist -> hierarchical scan -> scatter
    hist_kernel<<<(ET + 255) / 256, 256, 0, stream>>>(dst, deg);
    partial_kernel<<<SCAN_NB, 256, 0, stream>>>(deg, bsum);
    scanp_kernel<<<1, 256, 0, stream>>>(bsum, bbase);
    emit_kernel<<<SCAN_NB, 256, 0, stream>>>(deg, bbase, off, cur);
    scatter_kernel<<<(ET + 255) / 256, 256, 0, stream>>>(src, dst, cur, ssorted);

    // layer 1
    gemm1_mfma<<<(NN + 63) / 64, 256, 0, stream>>>(x, Wh1T, Wl1T, a_src1, a_dst1, hpre, s1s, s1d);
    fusedagg1_kernel<<<(NN + 3) / 4, 256, 0, stream>>>(off, ssorted, s1s, s1d, hpre, b1, h1);

    // layer 2
    gemm2_mfma<<<(NN + 63) / 64, 256, 0, stream>>>(h1, Wh2T, Wl2T, a_src2, a_dst2, z2, s2s, s2d);
    fusedagg2_kernel<<<(NN + 3) / 4, 256, 0, stream>>>(off, ssorted, s2s, s2d, z2, b2, out);
}

// Round 9
// 371.606 us; speedup vs baseline: 1.6455x; 1.0795x over previous
//
#include <hip/hip_runtime.h>
#include <hip/hip_bf16.h>
#include <math.h>

// GAT 2-layer, MI355X. CSR aggregation with fp16 gather tables (r9),
// MFMA GEMMs (3-term bf16 split ~ f32 accuracy), h1 as exact bf16 hi/lo pair.
#define NN 50000
#define NE 800000
#define ET 850000          // NE + NN self loops
#define DIN 512
#define F1 128             // HEADS*HIDDEN
#define NC 40
#define NEG 0.2f
#define CAP 128            // per-node cached-edge cap (max degree ~50 stat.)
#define SCAN_NB ((NN + 255) / 256)   // 196

typedef __attribute__((ext_vector_type(8))) short s16x8;
typedef __attribute__((ext_vector_type(4))) float f32x4;
typedef __attribute__((ext_vector_type(8))) _Float16 f16x8;

__device__ inline unsigned short bfh(float f) {
    __hip_bfloat16 h = __float2bfloat16(f);
    return __builtin_bit_cast(unsigned short, h);
}
__device__ inline float bff(unsigned short u) {
    unsigned int x = (unsigned int)u << 16;
    return __builtin_bit_cast(float, x);
}

__device__ inline void split8(f32x4 v0, f32x4 v1, s16x8* hi, s16x8* lo) {
    float f[8] = {v0.x, v0.y, v0.z, v0.w, v1.x, v1.y, v1.z, v1.w};
    #pragma unroll
    for (int j = 0; j < 8; ++j) {
        unsigned short h = bfh(f[j]);
        (*hi)[j] = (short)h;
        (*lo)[j] = (short)bfh(f[j] - bff(h));
    }
}

__device__ inline void gl16(const void* g, void* l) {
    __builtin_amdgcn_global_load_lds((const __attribute__((address_space(1))) unsigned int*)g,
                                     (__attribute__((address_space(3))) unsigned int*)l, 16, 0, 0);
}

// ---------------- prep: zero deg + weight splits (merged) ----------------
__global__ void prep_kernel(const float* __restrict__ W1,
        const float* __restrict__ W2, int* __restrict__ deg,
        unsigned short* __restrict__ Wh1T, unsigned short* __restrict__ Wl1T,
        unsigned short* __restrict__ Wh2T, unsigned short* __restrict__ Wl2T) {
    int i = blockIdx.x * blockDim.x + threadIdx.x;
    if (i < NN) deg[i] = 0;
    if (i < DIN * F1) {
        int k = i >> 7, c = i & 127;
        float w = W1[i];
        unsigned short h = bfh(w);
        unsigned short l = bfh(w - bff(h));
        Wh1T[c * DIN + k] = h;
        Wl1T[c * DIN + k] = l;
    }
    if (i < 48 * 128) {
        int c = i >> 7, k = i & 127;
        float w = (c < NC) ? W2[k * NC + c] : 0.f;
        unsigned short h = bfh(w);
        unsigned short l = bfh(w - bff(h));
        Wh2T[c * 128 + k] = h;
        Wl2T[c * 128 + k] = l;
    }
}

// ---------------- CSR build ----------------
__global__ void hist_kernel(const int* __restrict__ dst, int* __restrict__ deg) {
    int e = blockIdx.x * blockDim.x + threadIdx.x;
    if (e >= ET) return;
    int d = (e < NE) ? dst[e] : (e - NE);
    atomicAdd(&deg[d], 1);
}

__global__ __launch_bounds__(256) void partial_kernel(const int* __restrict__ deg,
        int* __restrict__ bsum) {
    __shared__ int red[4];
    int i = blockIdx.x * 256 + threadIdx.x;
    int v = (i < NN) ? deg[i] : 0;
    #pragma unroll
    for (int o = 1; o < 64; o <<= 1) v += __shfl_xor(v, o);
    if ((threadIdx.x & 63) == 0) red[threadIdx.x >> 6] = v;
    __syncthreads();
    if (threadIdx.x == 0) bsum[blockIdx.x] = red[0] + red[1] + red[2] + red[3];
}

__global__ __launch_bounds__(256) void scanp_kernel(const int* __restrict__ bsum,
        int* __restrict__ bbase) {
    __shared__ int s[256];
    int t = threadIdx.x;
    s[t] = (t < SCAN_NB) ? bsum[t] : 0;
    __syncthreads();
    #pragma unroll
    for (int o = 1; o < 256; o <<= 1) {
        int v = (t >= o) ? s[t - o] : 0;
        __syncthreads();
        s[t] += v;
        __syncthreads();
    }
    if (t < SCAN_NB) bbase[t] = (t == 0) ? 0 : s[t - 1];
}

__global__ __launch_bounds__(256) void emit_kernel(const int* __restrict__ deg,
        const int* __restrict__ bbase, int* __restrict__ off, int* __restrict__ cur) {
    __shared__ int s[256];
    int t = threadIdx.x;
    int i = blockIdx.x * 256 + t;
    int d = (i < NN) ? deg[i] : 0;
    s[t] = d;
    __syncthreads();
    #pragma unroll
    for (int o = 1; o < 256; o <<= 1) {
        int v = (t >= o) ? s[t - o] : 0;
        __syncthreads();
        s[t] += v;
        __syncthreads();
    }
    int o0 = bbase[blockIdx.x] + s[t] - d;   // exclusive
    if (i < NN) { off[i] = o0; cur[i] = o0; }
    if (i == NN - 1) off[NN] = o0 + d;
}

__global__ void scatter_kernel(const int* __restrict__ src, const int* __restrict__ dst,
        int* __restrict__ cur, int* __restrict__ ssorted) {
    int e = blockIdx.x * blockDim.x + threadIdx.x;
    if (e >= ET) return;
    int s = (e < NE) ? src[e] : (e - NE);
    int d = (e < NE) ? dst[e] : (e - NE);
    int pos = atomicAdd(&cur[d], 1);
    ssorted[pos] = s;
}

// ---------------- GEMM1 MFMA: [NN,512] x [512,128] -> H16 (fp16), + fused scores ----------------
__global__ __launch_bounds__(256) void gemm1_mfma(const float* __restrict__ X,
        const unsigned short* __restrict__ BhT, const unsigned short* __restrict__ BlT,
        const float* __restrict__ a_src, const float* __restrict__ a_dst,
        _Float16* __restrict__ H, float* __restrict__ s1s, float* __restrict__ s1d) {
    __shared__ char lds[49152];               // Ah 8K | Al 8K | Bh 16K | Bl 16K
    char* ldsAh = lds;
    char* ldsAl = lds + 8192;
    char* ldsBh = lds + 16384;
    char* ldsBl = lds + 32768;
    const int tid = threadIdx.x;
    const int wid = tid >> 6, lane = tid & 63;
    const int wm = wid >> 1, wn = wid & 1;
    const int l15 = lane & 15, lg = lane >> 4;
    const int row0 = blockIdx.x * 64;

    const int arow = tid >> 2;
    const int akc  = (tid & 3) * 16;
    const int asw  = (arow & 7) << 4;
    int agr = row0 + arow; if (agr > NN - 1) agr = NN - 1;
    const float* aptr = X + (long)agr * DIN + akc;

    f32x4 acc[2][4];
    #pragma unroll
    for (int mi = 0; mi < 2; ++mi)
        #pragma unroll
        for (int ni = 0; ni < 4; ++ni) acc[mi][ni] = (f32x4)(0.f);

    for (int k0 = 0; k0 < DIN; k0 += 64) {
        #pragma unroll
        for (int p = 0; p < 4; ++p) {
            int q = p * 256 + tid;
            int dstoff = (p * 256 + wid * 64) << 4;
            int rr = q >> 3;
            int w = (q & 7) << 4;
            int sw = (rr & 7) << 4;
            long sb = (long)rr * (DIN * 2) + k0 * 2 + (w ^ sw);
            gl16((const char*)BhT + sb, ldsBh + dstoff);
            gl16((const char*)BlT + sb, ldsBl + dstoff);
        }
        {
            f32x4 v0 = *(const f32x4*)(aptr + k0);
            f32x4 v1 = *(const f32x4*)(aptr + k0 + 4);
            f32x4 v2 = *(const f32x4*)(aptr + k0 + 8);
            f32x4 v3 = *(const f32x4*)(aptr + k0 + 12);
            s16x8 h0, l0, h1, l1;
            split8(v0, v1, &h0, &l0);
            split8(v2, v3, &h1, &l1);
            int b0 = arow * 128 + ((akc * 2) ^ asw);
            int b1 = arow * 128 + ((akc * 2 + 16) ^ asw);
            *(s16x8*)(ldsAh + b0) = h0;
            *(s16x8*)(ldsAh + b1) = h1;
            *(s16x8*)(ldsAl + b0) = l0;
            *(s16x8*)(ldsAl + b1) = l1;
        }
        __syncthreads();
        #pragma unroll
        for (int ks = 0; ks < 2; ++ks) {
            s16x8 ah[2], al[2], bh[4], bl[4];
            #pragma unroll
            for (int mi = 0; mi < 2; ++mi) {
                int row = wm * 32 + mi * 16 + l15;
                int sw = (row & 7) << 4;
                int kb = (ks * 32 + lg * 8) * 2;
                ah[mi] = *(const s16x8*)(ldsAh + row * 128 + (kb ^ sw));
                al[mi] = *(const s16x8*)(ldsAl + row * 128 + (kb ^ sw));
            }
            #pragma unroll
            for (int ni = 0; ni < 4; ++ni) {
                int col = wn * 64 + ni * 16 + l15;
                int sw = (col & 7) << 4;
                int kb = (ks * 32 + lg * 8) * 2;
                bh[ni] = *(const s16x8*)(ldsBh + col * 128 + (kb ^ sw));
                bl[ni] = *(const s16x8*)(ldsBl + col * 128 + (kb ^ sw));
            }
            #pragma unroll
            for (int mi = 0; mi < 2; ++mi)
                #pragma unroll
                for (int ni = 0; ni < 4; ++ni) {
                    acc[mi][ni] = __builtin_amdgcn_mfma_f32_16x16x32_bf16(ah[mi], bh[ni], acc[mi][ni], 0, 0, 0);
                    acc[mi][ni] = __builtin_amdgcn_mfma_f32_16x16x32_bf16(ah[mi], bl[ni], acc[mi][ni], 0, 0, 0);
                    acc[mi][ni] = __builtin_amdgcn_mfma_f32_16x16x32_bf16(al[mi], bh[ni], acc[mi][ni], 0, 0, 0);
                }
        }
        __syncthreads();
    }

    // store H as fp16 (only consumer is the layer-1 gather)
    #pragma unroll
    for (int mi = 0; mi < 2; ++mi)
        #pragma unroll
        for (int ni = 0; ni < 4; ++ni) {
            int col = wn * 64 + ni * 16 + l15;
            #pragma unroll
            for (int r = 0; r < 4; ++r) {
                int grow = row0 + wm * 32 + mi * 16 + lg * 4 + r;
                if (grow < NN) H[(long)grow * F1 + col] = (_Float16)acc[mi][ni][r];
            }
        }
    float av[4], bv[4];
    #pragma unroll
    for (int ni = 0; ni < 4; ++ni) {
        int col = wn * 64 + ni * 16 + l15;
        av[ni] = a_src[col];
        bv[ni] = a_dst[col];
    }
    #pragma unroll
    for (int mi = 0; mi < 2; ++mi)
        #pragma unroll
        for (int hl = 0; hl < 2; ++hl) {
            #pragma unroll
            for (int r = 0; r < 4; ++r) {
                float t1 = acc[mi][2 * hl][r] * av[2 * hl] + acc[mi][2 * hl + 1][r] * av[2 * hl + 1];
                float t2 = acc[mi][2 * hl][r] * bv[2 * hl] + acc[mi][2 * hl + 1][r] * bv[2 * hl + 1];
                #pragma unroll
                for (int o = 1; o < 16; o <<= 1) {
                    t1 += __shfl_xor(t1, o);
                    t2 += __shfl_xor(t2, o);
                }
                int grow = row0 + wm * 32 + mi * 16 + lg * 4 + r;
                if (l15 == 0 && grow < NN) {
                    int head = 2 * wn + hl;
                    s1s[grow * 4 + head] = t1;
                    s1d[grow * 4 + head] = t2;
                }
            }
        }
}

// ---------------- GEMM2 MFMA: [NN,128](bf16 hi/lo) x [128,40->48] -> Z16, + scores ----------------
__global__ __launch_bounds__(256) void gemm2_mfma(
        const unsigned short* __restrict__ H1h, const unsigned short* __restrict__ H1l,
        const unsigned short* __restrict__ B2h, const unsigned short* __restrict__ B2l,
        const float* __restrict__ a_src, const float* __restrict__ a_dst,
        _Float16* __restrict__ Z, float* __restrict__ s2s, float* __restrict__ s2d) {
    __shared__ char lds[57344];               // Ah 16K | Al 16K | Bh 12K | Bl 12K
    char* ldsAh = lds;
    char* ldsAl = lds + 16384;
    char* ldsBh = lds + 32768;
    char* ldsBl = lds + 45056;
    const int tid = threadIdx.x;
    const int wid = tid >> 6, lane = tid & 63;
    const int l15 = lane & 15, lg = lane >> 4;
    const int row0 = blockIdx.x * 64;

    // stage A hi/lo: 64 rows x 256 B = 1024 chunks each
    #pragma unroll
    for (int p = 0; p < 4; ++p) {
        int q = p * 256 + tid;
        int rr = q >> 4;
        int w = (q & 15) << 4;
        int sw = (rr & 7) << 4;
        int gr = row0 + rr; if (gr > NN - 1) gr = NN - 1;
        int dstoff = (p * 256 + wid * 64) << 4;
        gl16((const char*)(H1h + (long)gr * F1) + (w ^ sw), ldsAh + dstoff);
        gl16((const char*)(H1l + (long)gr * F1) + (w ^ sw), ldsAl + dstoff);
    }
    // stage B hi/lo: 48 rows x 256 B = 768 chunks each
    #pragma unroll
    for (int p = 0; p < 3; ++p) {
        int q = p * 256 + tid;
        int rr = q >> 4;
        int w = (q & 15) << 4;
        int sw = (rr & 7) << 4;
        int dstoff = (p * 256 + wid * 64) << 4;
        gl16((const char*)B2h + rr * 256 + (w ^ sw), ldsBh + dstoff);
        gl16((const char*)B2l + rr * 256 + (w ^ sw), ldsBl + dstoff);
    }
    __syncthreads();

    f32x4 acc[3];
    #pragma unroll
    for (int ni = 0; ni < 3; ++ni) acc[ni] = (f32x4)(0.f);

    #pragma unroll
    for (int ks = 0; ks < 4; ++ks) {
        int row = wid * 16 + l15;
        int sw = (row & 7) << 4;
        int kb = (ks * 32 + lg * 8) * 2;
        s16x8 ah = *(const s16x8*)(ldsAh + row * 256 + (kb ^ sw));
        s16x8 al = *(const s16x8*)(ldsAl + row * 256 + (kb ^ sw));
        #pragma unroll
        for (int ni = 0; ni < 3; ++ni) {
            int cc = ni * 16 + l15;
            int swb = (cc & 7) << 4;
            s16x8 bh = *(const s16x8*)(ldsBh + cc * 256 + (kb ^ swb));
            s16x8 bl = *(const s16x8*)(ldsBl + cc * 256 + (kb ^ swb));
            acc[ni] = __builtin_amdgcn_mfma_f32_16x16x32_bf16(ah, bh, acc[ni], 0, 0, 0);
            acc[ni] = __builtin_amdgcn_mfma_f32_16x16x32_bf16(ah, bl, acc[ni], 0, 0, 0);
            acc[ni] = __builtin_amdgcn_mfma_f32_16x16x32_bf16(al, bh, acc[ni], 0, 0, 0);
        }
    }

    float av[3], bv[3];
    #pragma unroll
    for (int ni = 0; ni < 3; ++ni) {
        int cc = ni * 16 + l15;
        av[ni] = (cc < NC) ? a_src[cc] : 0.f;
        bv[ni] = (cc < NC) ? a_dst[cc] : 0.f;
    }
    #pragma unroll
    for (int r = 0; r < 4; ++r) {
        int grow = row0 + wid * 16 + lg * 4 + r;
        bool ok = grow < NN;
        float t1 = acc[0][r] * av[0] + acc[1][r] * av[1] + acc[2][r] * av[2];
        float t2 = acc[0][r] * bv[0] + acc[1][r] * bv[1] + acc[2][r] * bv[2];
        #pragma unroll
        for (int o = 1; o < 16; o <<= 1) {
            t1 += __shfl_xor(t1, o);
            t2 += __shfl_xor(t2, o);
        }
        #pragma unroll
        for (int ni = 0; ni < 3; ++ni) {
            int cc = ni * 16 + l15;
            if (ok && cc < NC) Z[(long)grow * NC + cc] = (_Float16)acc[ni][r];
        }
        if (ok && l15 == 0) { s2s[grow] = t1; s2d[grow] = t2; }
    }
}

// ------------- fused layer-1 softmax + aggregate + bias + ELU -------------
// wave per dst node; pass 2: 4 edge-groups x 16 lanes x 8 fp16 feats (16 B/lane).
// output written as exact bf16 hi/lo pair for gemm2.
__global__ __launch_bounds__(256) void fusedagg1_kernel(
        const int* __restrict__ off, const int* __restrict__ ssorted,
        const float* __restrict__ ssrc, const float* __restrict__ sdst,
        const _Float16* __restrict__ H, const float* __restrict__ b,
        unsigned short* __restrict__ Oh, unsigned short* __restrict__ Ol) {
    __shared__ int idx_lds[4][CAP];
    __shared__ __align__(16) float e_lds[4][CAP][4];
    const int nd = threadIdx.x >> 6;
    int n = blockIdx.x * 4 + nd;
    if (n >= NN) return;
    const int lane = threadIdx.x & 63;
    const int base = off[n];
    const int deg  = off[n + 1] - base;
    const float4 vd = *(const float4*)(sdst + (long)n * 4);

    // pass 1a: logits -> LDS, track max
    float m0 = -1e30f, m1 = -1e30f, m2 = -1e30f, m3 = -1e30f;
    for (int k = lane; k < deg; k += 64) {
        int s = ssorted[base + k];
        float4 vs = *(const float4*)(ssrc + (long)s * 4);
        float x0 = vs.x + vd.x; x0 = (x0 > 0.f) ? x0 : NEG * x0;
        float x1 = vs.y + vd.y; x1 = (x1 > 0.f) ? x1 : NEG * x1;
        float x2 = vs.z + vd.z; x2 = (x2 > 0.f) ? x2 : NEG * x2;
        float x3 = vs.w + vd.w; x3 = (x3 > 0.f) ? x3 : NEG * x3;
        if (k < CAP) {
            idx_lds[nd][k] = s;
            *(f32x4*)&e_lds[nd][k][0] = (f32x4){x0, x1, x2, x3};
        }
        m0 = fmaxf(m0, x0); m1 = fmaxf(m1, x1);
        m2 = fmaxf(m2, x2); m3 = fmaxf(m3, x3);
    }
    #pragma unroll
    for (int o = 1; o < 64; o <<= 1) {
        m0 = fmaxf(m0, __shfl_xor(m0, o));
        m1 = fmaxf(m1, __shfl_xor(m1, o));
        m2 = fmaxf(m2, __shfl_xor(m2, o));
        m3 = fmaxf(m3, __shfl_xor(m3, o));
    }
    // pass 1b: e = exp(x-m) -> LDS, track sum
    float t0 = 0.f, t1 = 0.f, t2 = 0.f, t3 = 0.f;
    for (int k = lane; k < deg; k += 64) {
        float x0, x1, x2, x3;
        if (k < CAP) {
            f32x4 v = *(const f32x4*)&e_lds[nd][k][0];
            x0 = v.x; x1 = v.y; x2 = v.z; x3 = v.w;
        } else {
            int s = ssorted[base + k];
            float4 vs = *(const float4*)(ssrc + (long)s * 4);
            x0 = vs.x + vd.x; x0 = (x0 > 0.f) ? x0 : NEG * x0;
            x1 = vs.y + vd.y; x1 = (x1 > 0.f) ? x1 : NEG * x1;
            x2 = vs.z + vd.z; x2 = (x2 > 0.f) ? x2 : NEG * x2;
            x3 = vs.w + vd.w; x3 = (x3 > 0.f) ? x3 : NEG * x3;
        }
        float e0 = __expf(x0 - m0), e1 = __expf(x1 - m1);
        float e2 = __expf(x2 - m2), e3 = __expf(x3 - m3);
        if (k < CAP) *(f32x4*)&e_lds[nd][k][0] = (f32x4){e0, e1, e2, e3};
        t0 += e0; t1 += e1; t2 += e2; t3 += e3;
    }
    #pragma unroll
    for (int o = 1; o < 64; o <<= 1) {
        t0 += __shfl_xor(t0, o); t1 += __shfl_xor(t1, o);
        t2 += __shfl_xor(t2, o); t3 += __shfl_xor(t3, o);
    }
    // pass 2: edge-grouped gather. lane = g*16 + l; feats [8l, 8l+8), head=l>>2.
    const int g = lane >> 4;
    const int l = lane & 15;
    const int hd = l >> 2;
    const float mh  = (hd == 0) ? m0 : (hd == 1) ? m1 : (hd == 2) ? m2 : m3;
    const float th  = (hd == 0) ? t0 : (hd == 1) ? t1 : (hd == 2) ? t2 : t3;
    const float ih  = 1.f / (th + 1e-9f);
    const float vdh = (hd == 0) ? vd.x : (hd == 1) ? vd.y : (hd == 2) ? vd.z : vd.w;
    const int c0 = l * 8;
    f32x4 accA = (f32x4)(0.f), accB = (f32x4)(0.f);
    const int kend = (deg < CAP) ? deg : CAP;
    for (int k = g; k < kend; k += 4) {
        int s = idx_lds[nd][k];
        float e = e_lds[nd][k][hd];
        f16x8 hv = *(const f16x8*)(H + (long)s * F1 + c0);
        accA.x += e * (float)hv[0]; accA.y += e * (float)hv[1];
        accA.z += e * (float)hv[2]; accA.w += e * (float)hv[3];
        accB.x += e * (float)hv[4]; accB.y += e * (float)hv[5];
        accB.z += e * (float)hv[6]; accB.w += e * (float)hv[7];
    }
    for (int k = CAP + g; k < deg; k += 4) {   // statistically never taken
        int s = ssorted[base + k];
        float4 vs = *(const float4*)(ssrc + (long)s * 4);
        float x = ((hd == 0) ? vs.x : (hd == 1) ? vs.y : (hd == 2) ? vs.z : vs.w) + vdh;
        x = (x > 0.f) ? x : NEG * x;
        float e = __expf(x - mh);
        f16x8 hv = *(const f16x8*)(H + (long)s * F1 + c0);
        accA.x += e * (float)hv[0]; accA.y += e * (float)hv[1];
        accA.z += e * (float)hv[2]; accA.w += e * (float)hv[3];
        accB.x += e * (float)hv[4]; accB.y += e * (float)hv[5];
        accB.z += e * (float)hv[6]; accB.w += e * (float)hv[7];
    }
    // reduce across the 4 edge-groups
    #pragma unroll
    for (int o = 16; o < 64; o <<= 1) {
        accA.x += __shfl_xor(accA.x, o); accA.y += __shfl_xor(accA.y, o);
        accA.z += __shfl_xor(accA.z, o); accA.w += __shfl_xor(accA.w, o);
        accB.x += __shfl_xor(accB.x, o); accB.y += __shfl_xor(accB.y, o);
        accB.z += __shfl_xor(accB.z, o); accB.w += __shfl_xor(accB.w, o);
    }
    if (g == 0) {
        f32x4 bbA = *(const f32x4*)(b + c0);
        f32x4 bbB = *(const f32x4*)(b + c0 + 4);
        f32x4 vA = accA * (f32x4)(ih) + bbA;
        f32x4 vB = accB * (f32x4)(ih) + bbB;
        vA.x = (vA.x > 0.f) ? vA.x : expm1f(vA.x);
        vA.y = (vA.y > 0.f) ? vA.y : expm1f(vA.y);
        vA.z = (vA.z > 0.f) ? vA.z : expm1f(vA.z);
        vA.w = (vA.w > 0.f) ? vA.w : expm1f(vA.w);
        vB.x = (vB.x > 0.f) ? vB.x : expm1f(vB.x);
        vB.y = (vB.y > 0.f) ? vB.y : expm1f(vB.y);
        vB.z = (vB.z > 0.f) ? vB.z : expm1f(vB.z);
        vB.w = (vB.w > 0.f) ? vB.w : expm1f(vB.w);
        // exact bf16 hi/lo split (what gemm2's staging used to do)
        s16x8 hi, lo;
        split8(vA, vB, &hi, &lo);
        *(s16x8*)(Oh + (long)n * F1 + c0) = hi;
        *(s16x8*)(Ol + (long)n * F1 + c0) = lo;
    }
}

// ------------- fused layer-2 softmax + aggregate + bias + row softmax -------------
// pass 2: 8 edge-groups x 8 lanes x 5 fp16 classes.
__global__ __launch_bounds__(256) void fusedagg2_kernel(
        const int* __restrict__ off, const int* __restrict__ ssorted,
        const float* __restrict__ ssrc, const float* __restrict__ sdst,
        const _Float16* __restrict__ Z, const float* __restrict__ b,
        float* __restrict__ out) {
    __shared__ int   idx_lds[4][CAP];
    __shared__ float e_lds[4][CAP];
    const int nd = threadIdx.x >> 6;
    int n = blockIdx.x * 4 + nd;
    if (n >= NN) return;
    const int lane = threadIdx.x & 63;
    const int base = off[n];
    const int deg  = off[n + 1] - base;
    const float sdn = sdst[n];

    float m = -1e30f;
    for (int k = lane; k < deg; k += 64) {
        int s = ssorted[base + k];
        float x = ssrc[s] + sdn;
        x = (x > 0.f) ? x : NEG * x;
        if (k < CAP) { idx_lds[nd][k] = s; e_lds[nd][k] = x; }
        m = fmaxf(m, x);
    }
    #pragma unroll
    for (int o = 1; o < 64; o <<= 1) m = fmaxf(m, __shfl_xor(m, o));
    float t = 0.f;
    for (int k = lane; k < deg; k += 64) {
        float x;
        if (k < CAP) x = e_lds[nd][k];
        else {
            int s = ssorted[base + k];
            x = ssrc[s] + sdn;
            x = (x > 0.f) ? x : NEG * x;
        }
        float e = __expf(x - m);
        if (k < CAP) e_lds[nd][k] = e;
        t += e;
    }
    #pragma unroll
    for (int o = 1; o < 64; o <<= 1) t += __shfl_xor(t, o);
    const float inv = 1.f / (t + 1e-9f);

    // pass 2: lane = g*8 + l; classes [5l, 5l+5)
    const int g = lane >> 3;
    const int l = lane & 7;
    const int c0 = l * 5;
    float a0 = 0.f, a1 = 0.f, a2 = 0.f, a3 = 0.f, a4 = 0.f;
    const int kend = (deg < CAP) ? deg : CAP;
    for (int k = g; k < kend; k += 8) {
        int s = idx_lds[nd][k];
        float e = e_lds[nd][k];
        const _Float16* zp = Z + (long)s * NC + c0;
        a0 += e * (float)zp[0]; a1 += e * (float)zp[1]; a2 += e * (float)zp[2];
        a3 += e * (float)zp[3]; a4 += e * (float)zp[4];
    }
    for (int k = CAP + g; k < deg; k += 8) {   // statistically never taken
        int s = ssorted[base + k];
        float x = ssrc[s] + sdn;
        x = (x > 0.f) ? x : NEG * x;
        float e = __expf(x - m);
        const _Float16* zp = Z + (long)s * NC + c0;
        a0 += e * (float)zp[0]; a1 += e * (float)zp[1]; a2 += e * (float)zp[2];
        a3 += e * (float)zp[3]; a4 += e * (float)zp[4];
    }
    #pragma unroll
    for (int o = 8; o < 64; o <<= 1) {
        a0 += __shfl_xor(a0, o); a1 += __shfl_xor(a1, o);
        a2 += __shfl_xor(a2, o); a3 += __shfl_xor(a3, o);
        a4 += __shfl_xor(a4, o);
    }
    if (g == 0) {
        float v0 = a0 * inv + b[c0 + 0];
        float v1 = a1 * inv + b[c0 + 1];
        float v2 = a2 * inv + b[c0 + 2];
        float v3 = a3 * inv + b[c0 + 3];
        float v4 = a4 * inv + b[c0 + 4];
        // row softmax across lanes 0..7 (each 5 classes)
        float mx = fmaxf(fmaxf(fmaxf(v0, v1), fmaxf(v2, v3)), v4);
        #pragma unroll
        for (int o = 1; o < 8; o <<= 1) mx = fmaxf(mx, __shfl_xor(mx, o));
        float e0 = __expf(v0 - mx), e1 = __expf(v1 - mx), e2 = __expf(v2 - mx);
        float e3 = __expf(v3 - mx), e4 = __expf(v4 - mx);
        float s = e0 + e1 + e2 + e3 + e4;
        #pragma unroll
        for (int o = 1; o < 8; o <<= 1) s += __shfl_xor(s, o);
        float is = 1.f / s;
        float* op = out + (long)n * NC + c0;
        op[0] = e0 * is; op[1] = e1 * is; op[2] = e2 * is;
        op[3] = e3 * is; op[4] = e4 * is;
    }
}

extern "C" void kernel_launch(void* const* d_in, const int* in_sizes, int n_in,
                              void* d_out, int out_size, void* d_ws, size_t ws_size,
                              hipStream_t stream) {
    const float* x      = (const float*)d_in[0];
    const int*   src    = (const int*)  d_in[1];
    const int*   dst    = (const int*)  d_in[2];
    const float* W1     = (const float*)d_in[3];
    const float* a_src1 = (const float*)d_in[4];
    const float* a_dst1 = (const float*)d_in[5];
    const float* b1     = (const float*)d_in[6];
    const float* W2     = (const float*)d_in[7];
    const float* a_src2 = (const float*)d_in[8];
    const float* a_dst2 = (const float*)d_in[9];
    const float* b2     = (const float*)d_in[10];
    float* out = (float*)d_out;

    // ws layout (~49 MB, all 16B-aligned boundaries)
    float* ws   = (float*)d_ws;
    float* s1s  = ws;                   //   200,000 f32
    float* s1d  = s1s + 200000;         //   200,000
    float* s2s  = s1d + 200000;         //    50,000
    float* s2d  = s2s + 50000;          //    50,000   (500,000 f32 = 2,000,000 B)
    _Float16* H16 = (_Float16*)(s2d + 50000);            // 6,400,000 halves
    unsigned short* h1h = (unsigned short*)(H16 + 6400000); // 6,400,000
    unsigned short* h1l = h1h + 6400000;                 // 6,400,000
    _Float16* z16 = (_Float16*)(h1l + 6400000);          // 2,000,000 halves
    int*   deg     = (int*)(z16 + 2000000);   //  50,000
    int*   off     = deg + 50000;           //  50,008 (padded)
    int*   cur     = off + 50008;           //  50,000
    int*   ssorted = cur + 50000;           // 850,000
    int*   bsum    = ssorted + 850000;      //     256
    int*   bbase   = bsum + 256;            //     256
    unsigned short* Wh1T = (unsigned short*)(bbase + 256);      // 65,536
    unsigned short* Wl1T = Wh1T + 65536;                        // 65,536
    unsigned short* Wh2T = Wl1T + 65536;                        //  6,144
    unsigned short* Wl2T = Wh2T + 6144;                         //  6,144

    // prep: zero deg + weight splits
    prep_kernel<<<(DIN * F1 + 255) / 256, 256, 0, stream>>>(W1, W2, deg, Wh1T, Wl1T, Wh2T, Wl2T);

    // CSR build (by dst): hist -> hierarchical scan -> scatter
    hist_kernel<<<(ET + 255) / 256, 256, 0, stream>>>(dst, deg);
    partial_kernel<<<SCAN_NB, 256, 0, stream>>>(deg, bsum);
    scanp_kernel<<<1, 256, 0, stream>>>(bsum, bbase);
    emit_kernel<<<SCAN_NB, 256, 0, stream>>>(deg, bbase, off, cur);
    scatter_kernel<<<(ET + 255) / 256, 256, 0, stream>>>(src, dst, cur, ssorted);

    // layer 1
    gemm1_mfma<<<(NN + 63) / 64, 256, 0, stream>>>(x, Wh1T, Wl1T, a_src1, a_dst1, H16, s1s, s1d);
    fusedagg1_kernel<<<(NN + 3) / 4, 256, 0, stream>>>(off, ssorted, s1s, s1d, H16, b1, h1h, h1l);

    // layer 2
    gemm2_mfma<<<(NN + 63) / 64, 256, 0, stream>>>(h1h, h1l, Wh2T, Wl2T, a_src2, a_dst2, z16, s2s, s2d);
    fusedagg2_kernel<<<(NN + 3) / 4, 256, 0, stream>>>(off, ssorted, s2s, s2d, z16, b2, out);
}